// Round 4
// baseline (237.650 us; speedup 1.0000x reference)
//
#include <hip/hip_runtime.h>
#include <math.h>

#define B_    20000
#define K_    32
#define DIM_  256
#define H_    128
#define NENT_ 100000

typedef unsigned int   uint_t;
typedef unsigned short ushort_t;
typedef __attribute__((ext_vector_type(8))) short bf16x8;
typedef __attribute__((ext_vector_type(4))) float f32x4;

__device__ __forceinline__ float dot4(float4 a, float4 b) {
    return a.x * b.x + a.y * b.y + a.z * b.z + a.w * b.w;
}

__device__ __forceinline__ float wred64(float v) {
    #pragma unroll
    for (int m = 32; m >= 1; m >>= 1) v += __shfl_xor(v, m, 64);
    return v;
}

__device__ __forceinline__ ushort_t f2bf(float f) {
    uint_t x = __float_as_uint(f);
    uint_t r = (x + 0x7fffu + ((x >> 16) & 1u)) >> 16;   // RNE
    return (ushort_t)r;
}

__device__ __forceinline__ uint_t pack2(float lo, float hi) {
    return (uint_t)f2bf(lo) | ((uint_t)f2bf(hi) << 16);
}

// ============================================================================
// proj_direct: P[e][h] = scale_e*(ent[e].W[h]) bf16; sc1/sc2 = a1/a2 . P[e].
// Block = 128e x 128h x 256k, 4 waves each owning 32e (2 e-tiles).
// X (B-operand) fragments loaded DIRECTLY from global into registers
// (row-major read matches the verified B-frag layout: row = l&15,
// 8 consecutive k at (l>>4)*8). Only W staged in LDS (bf16, XOR-swizzled,
// one barrier). K-loop has no barriers -> compiler pipelines, 8 waves/CU TLP.
// ============================================================================
__launch_bounds__(256)
__global__ void proj_direct(const float* __restrict__ ent,
                            const float* __restrict__ Wm,
                            const float* __restrict__ av,
                            float* __restrict__ sc1,
                            float* __restrict__ sc2,
                            ushort_t* __restrict__ P) {
    __shared__ short Ws[128 * 256];   // 64 KB bf16, rows of 512 B, XOR-swizzled

    const int t    = threadIdx.x;
    const int gb   = blockIdx.x * 128;
    const int lane = t & 63;
    const int w    = t >> 6;
    const int l15  = lane & 15;
    const int l4   = lane >> 4;

    // ---- stage W: thread t -> row r = t>>1, k-half (t&1)*128 ----
    {
        const int r    = t >> 1;
        const int half = (t & 1) * 128;
        const float* wp = Wm + r * DIM_ + half;
        const int swz = (r & 7) << 4;
        #pragma unroll
        for (int jc = 0; jc < 16; ++jc) {
            float4 f0 = *(const float4*)(wp + jc * 8);
            float4 f1 = *(const float4*)(wp + jc * 8 + 4);
            union { bf16x8 v; ushort_t us[8]; } pk;
            pk.us[0] = f2bf(f0.x); pk.us[1] = f2bf(f0.y);
            pk.us[2] = f2bf(f0.z); pk.us[3] = f2bf(f0.w);
            pk.us[4] = f2bf(f1.x); pk.us[5] = f2bf(f1.y);
            pk.us[6] = f2bf(f1.z); pk.us[7] = f2bf(f1.w);
            const int off = (r * 512 + half * 2 + jc * 16) ^ swz;
            *(bf16x8*)((char*)Ws + off) = pk.v;
        }
    }

    // ---- load X fragments direct from global (B-operand), fp32 ssq ----
    const int ebase = gb + w * 32;
    bf16x8 bfr[2][8];
    float scale[2];
    #pragma unroll
    for (int et = 0; et < 2; ++et) {
        const int eg = min(ebase + et * 16 + l15, NENT_ - 1);
        const float* xp = ent + (size_t)eg * DIM_ + l4 * 8;
        float ssq = 0.f;
        #pragma unroll
        for (int kk = 0; kk < 8; ++kk) {
            float4 f0 = *(const float4*)(xp + kk * 32);
            float4 f1 = *(const float4*)(xp + kk * 32 + 4);
            ssq += dot4(f0, f0) + dot4(f1, f1);
            union { bf16x8 v; ushort_t us[8]; } pk;
            pk.us[0] = f2bf(f0.x); pk.us[1] = f2bf(f0.y);
            pk.us[2] = f2bf(f0.z); pk.us[3] = f2bf(f0.w);
            pk.us[4] = f2bf(f1.x); pk.us[5] = f2bf(f1.y);
            pk.us[6] = f2bf(f1.z); pk.us[7] = f2bf(f1.w);
            bfr[et][kk] = pk.v;
        }
        // full row-ssq lives in the 4 lanes sharing l15
        ssq += __shfl_xor(ssq, 16, 64);
        ssq += __shfl_xor(ssq, 32, 64);
        scale[et] = fminf(1.f, 1.f / fmaxf(sqrtf(ssq), 1e-12f));
    }

    __syncthreads();   // W staged

    // ---- h-tile loop: ds_read A-frags + MFMA, epilogue per tile ----
    float s1[2] = {0.f, 0.f}, s2[2] = {0.f, 0.f};
    #pragma unroll 2
    for (int ht = 0; ht < 8; ++ht) {
        const int hrow = ht * 16 + l15;
        const int hswz = (hrow & 7) << 4;
        bf16x8 af[8];
        #pragma unroll
        for (int kk = 0; kk < 8; ++kk)
            af[kk] = *(const bf16x8*)((const char*)Ws +
                     ((hrow * 512 + kk * 64 + l4 * 16) ^ hswz));
        f32x4 acc0 = (f32x4){0.f, 0.f, 0.f, 0.f};
        f32x4 acc1 = (f32x4){0.f, 0.f, 0.f, 0.f};
        #pragma unroll
        for (int kk = 0; kk < 8; ++kk) {
            acc0 = __builtin_amdgcn_mfma_f32_16x16x32_bf16(af[kk], bfr[0][kk], acc0, 0, 0, 0);
            acc1 = __builtin_amdgcn_mfma_f32_16x16x32_bf16(af[kk], bfr[1][kk], acc1, 0, 0, 0);
        }
        // epilogue: lane holds e = l15 (col), h = ht*16 + l4*4 + reg
        const int hb = ht * 16 + l4 * 4;
        const float4 a1v = *(const float4*)(av + hb);
        const float4 a2v = *(const float4*)(av + H_ + hb);
        #pragma unroll
        for (int et = 0; et < 2; ++et) {
            const f32x4 v = et ? acc1 : acc0;
            const float scl = scale[et];
            const float v0 = v[0] * scl, v1 = v[1] * scl;
            const float v2 = v[2] * scl, v3 = v[3] * scl;
            s1[et] += a1v.x * v0 + a1v.y * v1 + a1v.z * v2 + a1v.w * v3;
            s2[et] += a2v.x * v0 + a2v.y * v1 + a2v.z * v2 + a2v.w * v3;
            const int eg = ebase + et * 16 + l15;
            if (eg < NENT_) {
                uint2 pk;
                pk.x = pack2(v0, v1);
                pk.y = pack2(v2, v3);
                *(uint2*)(P + (size_t)eg * H_ + hb) = pk;
            }
        }
    }

    // ---- sc1/sc2: reduce over the 4 lanes sharing e, store from l4==0 ----
    #pragma unroll
    for (int et = 0; et < 2; ++et) {
        float a1 = s1[et], a2 = s2[et];
        a1 += __shfl_xor(a1, 16, 64);
        a1 += __shfl_xor(a1, 32, 64);
        a2 += __shfl_xor(a2, 16, 64);
        a2 += __shfl_xor(a2, 32, 64);
        const int eg = ebase + et * 16 + l15;
        if (l4 == 0 && eg < NENT_) {
            sc1[eg] = a1;
            sc2[eg] = a2;
        }
    }
}

// ============================================================================
// main_kernel: one wave per batch item. T14 issue-early: all 8 P-row gathers
// issued before the softmax/user VALU work so L3 latency hides under it.
// ============================================================================
__launch_bounds__(256)
__global__ void main_kernel(const int* __restrict__ u,
                            const int* __restrict__ t_idx,
                            const int* __restrict__ n_idx,
                            const float* __restrict__ usr,
                            const float* __restrict__ sc1,
                            const float* __restrict__ sc2,
                            const ushort_t* __restrict__ P,
                            float* __restrict__ out) {
    const int wave = threadIdx.x >> 6;
    const int lane = threadIdx.x & 63;
    const int b    = blockIdx.x * 4 + wave;
    const int j    = lane & 31;   // neighbor index
    const int q    = lane >> 4;   // 0..3: k-phase of the gather loop
    const int c    = lane & 15;   // 16-B chunk -> h = 8c..8c+7

    // ---- issue all 8 P gathers first (lane covers k = i*4+q) ----
    const int nk = n_idx[b * K_ + j];
    int nm[8];
    #pragma unroll
    for (int i = 0; i < 8; ++i) nm[i] = __shfl(nk, i * 4 + q);
    uint4 pv[8];
    #pragma unroll
    for (int i = 0; i < 8; ++i)
        pv[i] = *(const uint4*)((const char*)P + (size_t)nm[i] * 256 + c * 16);

    // ---- user fragments (issue early too) ----
    const float* ubp = usr + (size_t)u[b] * DIM_;
    float4 ua0 = *(const float4*)(ubp + 8 * c);
    float4 ua1 = *(const float4*)(ubp + 8 * c + 4);
    float4 ub0 = *(const float4*)(ubp + H_ + 8 * c);
    float4 ub1 = *(const float4*)(ubp + H_ + 8 * c + 4);

    // ---- scores + softmax over 32 (duplicated across wave halves) ----
    float s = sc1[t_idx[b]] + sc2[nk];
    s = (s >= 0.f) ? s : 0.2f * s;
    float mx = s;
    #pragma unroll
    for (int m = 16; m >= 1; m >>= 1) mx = fmaxf(mx, __shfl_xor(mx, m, 64));
    float ex = __expf(s - mx);
    float sm = ex;
    #pragma unroll
    for (int m = 16; m >= 1; m >>= 1) sm += __shfl_xor(sm, m, 64);
    const float alpha = ex / sm;

    // ---- user norm from fragments (each 16-lane c-group covers the row) ----
    float ss = dot4(ua0, ua0) + dot4(ua1, ua1) + dot4(ub0, ub0) + dot4(ub1, ub1);
    #pragma unroll
    for (int m = 8; m >= 1; m >>= 1) ss += __shfl_xor(ss, m, 64);
    const float scl = fminf(1.f, 1.f / fmaxf(sqrtf(ss), 1e-12f));
    float uc[8];
    uc[0] = scl * (ua0.x + ub0.x); uc[1] = scl * (ua0.y + ub0.y);
    uc[2] = scl * (ua0.z + ub0.z); uc[3] = scl * (ua0.w + ub0.w);
    uc[4] = scl * (ua1.x + ub1.x); uc[5] = scl * (ua1.y + ub1.y);
    uc[6] = scl * (ua1.z + ub1.z); uc[7] = scl * (ua1.w + ub1.w);

    // ---- sp = sum_i alpha_i * (uc . P_row_i) ----
    float sp = 0.f;
    #pragma unroll
    for (int i = 0; i < 8; ++i) {
        const float am = __shfl(alpha, i * 4 + q);
        const uint4 v = pv[i];
        float d;
        d  = uc[0] * __uint_as_float(v.x << 16);
        d += uc[1] * __uint_as_float(v.x & 0xffff0000u);
        d += uc[2] * __uint_as_float(v.y << 16);
        d += uc[3] * __uint_as_float(v.y & 0xffff0000u);
        d += uc[4] * __uint_as_float(v.z << 16);
        d += uc[5] * __uint_as_float(v.z & 0xffff0000u);
        d += uc[6] * __uint_as_float(v.w << 16);
        d += uc[7] * __uint_as_float(v.w & 0xffff0000u);
        sp += am * d;
    }
    sp = wred64(sp);
    if (lane == 0) out[b] = 1.f / (1.f + __expf(-sp));
}

// ============================================================================
// Fallback (round-1 path) if workspace is too small for the tables.
// ============================================================================
__global__ void precompute_v12(const float* __restrict__ W,
                               const float* __restrict__ a,
                               float* __restrict__ v12) {
    int d = blockIdx.x * blockDim.x + threadIdx.x;
    if (d >= DIM_) return;
    float acc1 = 0.f, acc2 = 0.f;
    for (int h = 0; h < H_; ++h) {
        float w = W[h * DIM_ + d];
        acc1 += a[h] * w;
        acc2 += a[H_ + h] * w;
    }
    v12[d] = acc1;
    v12[DIM_ + d] = acc2;
}

__launch_bounds__(256)
__global__ void gat_main(const int* __restrict__ u,
                         const int* __restrict__ t_idx,
                         const int* __restrict__ n_idx,
                         const float* __restrict__ ent,
                         const float* __restrict__ usr,
                         const float* __restrict__ W,
                         const float* __restrict__ v12,
                         float* __restrict__ out) {
    const int b    = blockIdx.x;
    const int tid  = threadIdx.x;
    const int wave = tid >> 6;
    const int lane = tid & 63;

    __shared__ float xn_s[K_][DIM_];
    __shared__ float scr_s[K_];
    __shared__ float alpha_s[K_];
    __shared__ float uc_s[H_];
    __shared__ float red_s[4];

    const float4 v1_4 = ((const float4*)v12)[lane];
    const float4 v2_4 = ((const float4*)(v12 + DIM_))[lane];

    const int t = t_idx[b];
    float4 t4 = ((const float4*)(ent + (size_t)t * DIM_))[lane];
    float ss_t = wred64(dot4(t4, t4));
    float scl_t = fminf(1.0f, 1.0f / fmaxf(sqrtf(ss_t), 1e-12f));
    float s0 = scl_t * wred64(dot4(t4, v1_4));

    const int uid = u[b];
    float4 u4 = ((const float4*)(usr + (size_t)uid * DIM_))[lane];
    float ss_u = wred64(dot4(u4, u4));
    float scl_u = fminf(1.0f, 1.0f / fmaxf(sqrtf(ss_u), 1e-12f));
    float px = __shfl(u4.x, lane + 32);
    float py = __shfl(u4.y, lane + 32);
    float pz = __shfl(u4.z, lane + 32);
    float pw = __shfl(u4.w, lane + 32);
    if (wave == 0 && lane < 32) {
        float4 uc4;
        uc4.x = scl_u * (u4.x + px);
        uc4.y = scl_u * (u4.y + py);
        uc4.z = scl_u * (u4.z + pz);
        uc4.w = scl_u * (u4.w + pw);
        ((float4*)uc_s)[lane] = uc4;
    }

    for (int kk = 0; kk < 8; ++kk) {
        const int k   = wave * 8 + kk;
        const int idx = n_idx[b * K_ + k];
        float4 e4 = ((const float4*)(ent + (size_t)idx * DIM_))[lane];
        float ssk = wred64(dot4(e4, e4));
        float sk  = fminf(1.0f, 1.0f / fmaxf(sqrtf(ssk), 1e-12f));
        float dv2 = wred64(dot4(e4, v2_4));
        float4 xs;
        xs.x = e4.x * sk; xs.y = e4.y * sk; xs.z = e4.z * sk; xs.w = e4.w * sk;
        ((float4*)xn_s[k])[lane] = xs;
        if (lane == 0) {
            float sc = s0 + sk * dv2;
            scr_s[k] = (sc >= 0.f) ? sc : 0.2f * sc;
        }
    }
    __syncthreads();

    if (tid < 32) {
        float e = scr_s[tid];
        float mx = e;
        #pragma unroll
        for (int m = 16; m >= 1; m >>= 1) mx = fmaxf(mx, __shfl_xor(mx, m, 64));
        float ex = expf(e - mx);
        float sm = ex;
        #pragma unroll
        for (int m = 16; m >= 1; m >>= 1) sm += __shfl_xor(sm, m, 64);
        alpha_s[tid] = ex / sm;
    }
    __syncthreads();

    float m_d = 0.f;
    #pragma unroll
    for (int k = 0; k < K_; ++k) m_d += alpha_s[k] * xn_s[k][tid];

    const float* wcol = W + tid;
    float acc = 0.f;
    #pragma unroll 4
    for (int hh = 0; hh < H_; ++hh) acc += uc_s[hh] * wcol[(size_t)hh * DIM_];

    float p = wred64(acc * m_d);
    if (lane == 0) red_s[wave] = p;
    __syncthreads();
    if (tid == 0) {
        float uv = red_s[0] + red_s[1] + red_s[2] + red_s[3];
        out[b] = 1.0f / (1.0f + expf(-uv));
    }
}

extern "C" void kernel_launch(void* const* d_in, const int* in_sizes, int n_in,
                              void* d_out, int out_size, void* d_ws, size_t ws_size,
                              hipStream_t stream) {
    const int*   u     = (const int*)d_in[0];
    const int*   t_idx = (const int*)d_in[1];
    const int*   n_idx = (const int*)d_in[2];
    const float* ent   = (const float*)d_in[3];
    const float* usr   = (const float*)d_in[4];
    const float* W     = (const float*)d_in[5];
    const float* a     = (const float*)d_in[6];
    float*       out   = (float*)d_out;

    // ws layout: sc1 [100000 f32] | sc2 [100000 f32] | P [100000*128 bf16]
    const size_t SC1_OFF = 0;
    const size_t SC2_OFF = (size_t)NENT_ * 4;
    const size_t P_OFF   = (size_t)NENT_ * 8;
    const size_t NEED    = P_OFF + (size_t)NENT_ * H_ * 2;

    if (ws_size >= NEED) {
        float*    sc1 = (float*)((char*)d_ws + SC1_OFF);
        float*    sc2 = (float*)((char*)d_ws + SC2_OFF);
        ushort_t* P   = (ushort_t*)((char*)d_ws + P_OFF);

        hipLaunchKernelGGL(proj_direct, dim3((NENT_ + 127) / 128), dim3(256), 0, stream,
                           ent, W, a, sc1, sc2, P);
        hipLaunchKernelGGL(main_kernel, dim3(B_ / 4), dim3(256), 0, stream,
                           u, t_idx, n_idx, usr, sc1, sc2, P, out);
    } else {
        float* v12 = (float*)d_ws;   // 512 floats
        hipLaunchKernelGGL(precompute_v12, dim3(1), dim3(256), 0, stream, W, a, v12);
        hipLaunchKernelGGL(gat_main, dim3(B_), dim3(256), 0, stream,
                           u, t_idx, n_idx, ent, usr, W, v12, out);
    }
}